// Round 7
// baseline (43.706 us; speedup 1.0000x reference)
//
#include <hip/hip_runtime.h>

#define BATCH 8
#define CIN   64
#define COUT  64
#define LEN   16384
#define KS    5
#define PADW  2
#define LP    (LEN + 2*PADW)
#define TT    64
#define XW    96            // staged window rows (padded coords)
#define XST   97            // xt row stride in words (97 % 32 = 1 -> bank spread)
#define XM    14            // window start S0 = t0 - XM

typedef __attribute__((ext_vector_type(8)))  short short8;
typedef __attribute__((ext_vector_type(4)))  float f32x4;
typedef __attribute__((ext_vector_type(8)))  unsigned short ushort8;

__device__ __forceinline__ unsigned short bf16r(float f) {
    unsigned u = __builtin_bit_cast(unsigned, f);
    u += 0x7FFF + ((u >> 16) & 1);          // RNE
    return (unsigned short)(u >> 16);
}

__device__ __forceinline__ int reflmap(int s) {  // padded idx -> x idx
    return (s < PADW) ? (PADW - s) : ((s < LEN + PADW) ? (s - PADW) : (2*LEN - s));
}

// W (f32 [o][c][k]) -> bf16 A-frags for mfma_f32_16x16x32_bf16, K k-major
// (ck' = ktap*64 + c).  wf[((ot*10 + kk)*64 + lane)*8 + bidx]
__global__ void wfrag_kernel(const float* __restrict__ w, unsigned short* __restrict__ wf) {
    int el = blockIdx.x * 256 + threadIdx.x;          // 20480 total
    int bidx = el & 7;
    int lane = (el >> 3) & 63;
    int kk   = (el >> 9) % 10;
    int ot   = el / 5120;
    int o    = ot * 16 + (lane & 15);
    int kg   = kk * 32 + ((lane >> 4) << 3) + bidx;   // ck' 0..319
    int ktap = kg >> 6;
    int c    = kg & 63;
    wf[el] = bf16r(w[(o * 64 + c) * 5 + ktap]);
}

__global__ __launch_bounds__(128) void deform_mfma_kernel(
    const float* __restrict__ x, const float* __restrict__ offs,
    const unsigned short* __restrict__ wf, const float* __restrict__ bias,
    float* __restrict__ out)
{
    __shared__ float xt[CIN * XST];          // 24832 B

    const int tid = threadIdx.x;             // 128 threads = 2 waves
    const int bt  = blockIdx.x;
    const int b   = bt >> 8;
    const int t0  = (bt & 255) * TT;
    const int w   = tid >> 6;                // wave 0..1
    const int lane = tid & 63;
    const int s   = lane >> 4;               // k-chunk slot / A kq group
    const int colA = t0 + w * 32 + (lane & 15);
    const int colB = colA + 16;
    const int S0  = t0 - XM;                 // padded coord of xt row 0

    const float* xb0 = x + (size_t)b * CIN * LEN;

    // ---- load offsets early (independent of staging; latency overlaps it) ----
    float ofA[KS], ofB[KS];
    #pragma unroll
    for (int k = 0; k < KS; ++k) {
        ofA[k] = offs[(size_t)(b * LEN + colA) * KS + k];
        ofB[k] = offs[(size_t)(b * LEN + colB) * KS + k];
    }

    // ---- stage xp window into xt[c][r], stride 97 (xt[c*XST+r] = xp[S0+r]) ----
    if (S0 >= PADW && S0 - PADW + XW <= LEN) {
        const float* src0 = xb0 + (S0 - PADW);       // t0-16: 16B aligned
        #pragma unroll
        for (int rep = 0; rep < 12; ++rep) {
            int cid = rep * 128 + tid;               // 0..1535
            int c = cid / 24, q = cid - c * 24;
            float4 vv = *(const float4*)(src0 + (size_t)c * LEN + 4 * q);
            float* dst = &xt[c * XST + 4 * q];
            dst[0] = vv.x; dst[1] = vv.y; dst[2] = vv.z; dst[3] = vv.w;
        }
    } else {                                         // 2 edge tiles per batch row
        #pragma unroll
        for (int rep = 0; rep < 48; ++rep) {
            int idx = rep * 128 + tid;               // 0..6143
            int c = idx / XW, r = idx - c * XW;
            int sp = S0 + r;
            sp = min(max(sp, 0), LP - 1);
            xt[c * XST + r] = xb0[(size_t)c * LEN + reflmap(sp)];
        }
    }

    // ---- per-thread (i0, frac) for both columns, k = 0..4 ----
    int i0A[KS], i0B[KS], r0A[KS], r0B[KS];
    float frA[KS], frB[KS];
    bool fast = true;
    #pragma unroll
    for (int k = 0; k < KS; ++k) {
        float TA = (float)(colA + k) + ofA[k];
        TA = fminf(fmaxf(TA, 0.0f), (float)(LP - 1));
        int iA = (int)floorf(TA); iA = min(iA, LP - 2); iA = max(iA, 0);
        i0A[k] = iA; frA[k] = TA - (float)iA; r0A[k] = iA - S0;
        fast = fast && ((unsigned)(iA - S0) <= (unsigned)(XW - 2));
        float TB = (float)(colB + k) + ofB[k];
        TB = fminf(fmaxf(TB, 0.0f), (float)(LP - 1));
        int iB = (int)floorf(TB); iB = min(iB, LP - 2); iB = max(iB, 0);
        i0B[k] = iB; frB[k] = TB - (float)iB; r0B[k] = iB - S0;
        fast = fast && ((unsigned)(iB - S0) <= (unsigned)(XW - 2));
    }
    __syncthreads();

    f32x4 accA0 = {}, accA1 = {}, accA2 = {}, accA3 = {};
    f32x4 accB0 = {}, accB1 = {}, accB2 = {}, accB3 = {};
    const unsigned short* wfl = wf + (size_t)lane * 8;

#define GATHER(pk, r0v, i0v, fv, c0, CHECKED)                                  \
    {                                                                          \
        const float f = fv;                                                    \
        if (!(CHECKED) || (unsigned)(r0v) <= (unsigned)(XW - 2)) {             \
            const float* p = &xt[(c0) * XST + (r0v)];                          \
            _Pragma("unroll")                                                  \
            for (int e = 0; e < 8; ++e) {                                      \
                float g0 = p[0], g1 = p[1];                                    \
                pk[e] = bf16r(fmaf(f, g1 - g0, g0));                           \
                p += XST;                                                      \
            }                                                                  \
        } else {                                                               \
            int j0 = reflmap(i0v), j1 = reflmap((i0v) + 1);                    \
            const float* xc = xb0 + (size_t)(c0) * LEN;                        \
            _Pragma("unroll")                                                  \
            for (int e = 0; e < 8; ++e) {                                      \
                float g0 = xc[j0], g1 = xc[j1];                                \
                pk[e] = bf16r(fmaf(f, g1 - g0, g0));                           \
                xc += LEN;                                                     \
            }                                                                  \
        }                                                                      \
    }

#define GSTEP(kk, CHECKED)                                                     \
    {                                                                          \
        const int k  = (kk) >> 1;                                              \
        const int c0 = ((((kk) & 1) << 2) + s) << 3;                           \
        ushort8 pa, pb;                                                        \
        GATHER(pa, r0A[k], i0A[k], frA[k], c0, CHECKED)                        \
        GATHER(pb, r0B[k], i0B[k], frB[k], c0, CHECKED)                        \
        short8 bvA = __builtin_bit_cast(short8, pa);                           \
        short8 bvB = __builtin_bit_cast(short8, pb);                           \
        short8 a0 = *(const short8*)&wfl[(0 * 10 + (kk)) * 512];               \
        short8 a1 = *(const short8*)&wfl[(1 * 10 + (kk)) * 512];               \
        short8 a2 = *(const short8*)&wfl[(2 * 10 + (kk)) * 512];               \
        short8 a3 = *(const short8*)&wfl[(3 * 10 + (kk)) * 512];               \
        accA0 = __builtin_amdgcn_mfma_f32_16x16x32_bf16(a0, bvA, accA0, 0, 0, 0); \
        accB0 = __builtin_amdgcn_mfma_f32_16x16x32_bf16(a0, bvB, accB0, 0, 0, 0); \
        accA1 = __builtin_amdgcn_mfma_f32_16x16x32_bf16(a1, bvA, accA1, 0, 0, 0); \
        accB1 = __builtin_amdgcn_mfma_f32_16x16x32_bf16(a1, bvB, accB1, 0, 0, 0); \
        accA2 = __builtin_amdgcn_mfma_f32_16x16x32_bf16(a2, bvA, accA2, 0, 0, 0); \
        accB2 = __builtin_amdgcn_mfma_f32_16x16x32_bf16(a2, bvB, accB2, 0, 0, 0); \
        accA3 = __builtin_amdgcn_mfma_f32_16x16x32_bf16(a3, bvA, accA3, 0, 0, 0); \
        accB3 = __builtin_amdgcn_mfma_f32_16x16x32_bf16(a3, bvB, accB3, 0, 0, 0); \
    }

    if (fast) {
        GSTEP(0,0) GSTEP(1,0) GSTEP(2,0) GSTEP(3,0) GSTEP(4,0)
        GSTEP(5,0) GSTEP(6,0) GSTEP(7,0) GSTEP(8,0) GSTEP(9,0)
    } else {
        GSTEP(0,1) GSTEP(1,1) GSTEP(2,1) GSTEP(3,1) GSTEP(4,1)
        GSTEP(5,1) GSTEP(6,1) GSTEP(7,1) GSTEP(8,1) GSTEP(9,1)
    }
#undef GSTEP
#undef GATHER

    // ---- epilogue: C/D col=lane&15, row=(lane>>4)*4+r ----
    #pragma unroll
    for (int ot = 0; ot < 4; ++ot) {
        const f32x4 aA = (ot == 0) ? accA0 : (ot == 1) ? accA1 : (ot == 2) ? accA2 : accA3;
        const f32x4 aB = (ot == 0) ? accB0 : (ot == 1) ? accB1 : (ot == 2) ? accB2 : accB3;
        #pragma unroll
        for (int r = 0; r < 4; ++r) {
            int o = ot * 16 + s * 4 + r;
            float bv = bias[o];
            out[((size_t)(b * COUT + o)) * LEN + colA] = aA[r] + bv;
            out[((size_t)(b * COUT + o)) * LEN + colB] = aB[r] + bv;
        }
    }
}

extern "C" void kernel_launch(void* const* d_in, const int* in_sizes, int n_in,
                              void* d_out, int out_size, void* d_ws, size_t ws_size,
                              hipStream_t stream) {
    const float* x    = (const float*)d_in[0];
    const float* offs = (const float*)d_in[1];
    const float* w    = (const float*)d_in[2];
    const float* bias = (const float*)d_in[3];
    float* out = (float*)d_out;
    unsigned short* wf = (unsigned short*)d_ws;   // 40960 B

    wfrag_kernel<<<80, 256, 0, stream>>>(w, wf);
    deform_mfma_kernel<<<BATCH * (LEN / TT), 128, 0, stream>>>(x, offs, wf, bias, out);
}

// Round 8
// 39.632 us; speedup vs baseline: 1.1028x; 1.1028x over previous
//
#include <hip/hip_runtime.h>

#define BATCH 8
#define CIN   64
#define COUT  64
#define LEN   16384
#define KS    5
#define PADW  2
#define LP    (LEN + 2*PADW)
#define TT    64
#define XW    96            // pair-words per channel: r in [0,95], values xp[S0..S0+96]
#define XM    14            // window start S0 = t0 - XM (padded coords)

typedef __attribute__((ext_vector_type(8)))  short short8;
typedef __attribute__((ext_vector_type(4)))  float f32x4;
typedef __attribute__((ext_vector_type(8)))  unsigned short ushort8;

__device__ __forceinline__ unsigned short bf16r(float f) {
    unsigned u = __builtin_bit_cast(unsigned, f);
    u += 0x7FFF + ((u >> 16) & 1);          // RNE
    return (unsigned short)(u >> 16);
}

__device__ __forceinline__ int reflmap(int s) {  // padded idx -> x idx
    return (s < PADW) ? (PADW - s) : ((s < LEN + PADW) ? (s - PADW) : (2*LEN - s));
}

// xt word address: [r][c] with per-row XOR swizzle of 4-word blocks
__device__ __forceinline__ int xtaddr(int r, int c) {
    return r * 64 + (((c >> 2) ^ (r & 15)) << 2) + (c & 3);
}

// W (f32 [o][c][k]) -> bf16 A-frags for mfma_f32_16x16x32_bf16, K k-major
// (ck' = ktap*64 + c).  wf[((ot*10 + kk)*64 + lane)*8 + bidx]
__global__ void wfrag_kernel(const float* __restrict__ w, unsigned short* __restrict__ wf) {
    int el = blockIdx.x * 256 + threadIdx.x;          // 20480 total
    int bidx = el & 7;
    int lane = (el >> 3) & 63;
    int kk   = (el >> 9) % 10;
    int ot   = el / 5120;
    int o    = ot * 16 + (lane & 15);
    int kg   = kk * 32 + ((lane >> 4) << 3) + bidx;   // ck' 0..319
    int ktap = kg >> 6;
    int c    = kg & 63;
    wf[el] = bf16r(w[(o * 64 + c) * 5 + ktap]);
}

__global__ __launch_bounds__(256) void deform_mfma_kernel(
    const float* __restrict__ x, const float* __restrict__ offs,
    const unsigned short* __restrict__ wf, const float* __restrict__ bias,
    float* __restrict__ out)
{
    __shared__ __align__(16) unsigned int xt[XW * 64];   // 24576 B, pair-words

    const int tid = threadIdx.x;             // 256 threads = 4 waves
    const int bt  = blockIdx.x;
    const int b   = bt >> 8;
    const int t0  = (bt & 255) * TT;
    const int w   = tid >> 6;
    const int lane = tid & 63;
    const int s   = lane >> 4;               // k-chunk slot / A kq group
    const int tc  = t0 + w * 16 + (lane & 15);
    const int S0  = t0 - XM;                 // padded coord of xt row 0

    const float* xb0 = x + (size_t)b * CIN * LEN;

    // ---- load offsets early (latency hides under staging) ----
    float ofr[KS];
    #pragma unroll
    for (int k = 0; k < KS; ++k)
        ofr[k] = offs[(size_t)(b * LEN + tc) * KS + k];

    // ---- stage xp window as bf16 pairs: xt[r][c] = (xp[S0+r], xp[S0+r+1]) ----
    if (S0 >= PADW && S0 - PADW + 97 <= LEN) {
        const float* src0 = xb0 + (S0 - PADW);       // t0-16: 16B aligned
        #pragma unroll
        for (int j = 0; j < 3; ++j) {
            int task = j * 256 + tid;                // 0..767 = 64 ch x 12 strips
            int c = task / 12, q = task - c * 12;
            const float* p = src0 + (size_t)c * LEN + 8 * q;
            float4 va = *(const float4*)p;
            float4 vb = *(const float4*)(p + 4);
            float  v8 = p[8];
            unsigned short bb[9] = { bf16r(va.x), bf16r(va.y), bf16r(va.z), bf16r(va.w),
                                     bf16r(vb.x), bf16r(vb.y), bf16r(vb.z), bf16r(vb.w),
                                     bf16r(v8) };
            #pragma unroll
            for (int i = 0; i < 8; ++i) {
                int r = 8 * q + i;
                xt[xtaddr(r, c)] = (unsigned)bb[i] | ((unsigned)bb[i + 1] << 16);
            }
        }
    } else {                                         // edge tiles: reflect per element
        #pragma unroll
        for (int j = 0; j < 24; ++j) {
            int idx = j * 256 + tid;                 // 0..6143
            int r = idx >> 6, c = idx & 63;
            int sl = min(max(S0 + r,     0), LP - 1);
            int sh = min(max(S0 + r + 1, 0), LP - 1);
            unsigned short lo = bf16r(xb0[(size_t)c * LEN + reflmap(sl)]);
            unsigned short hi = bf16r(xb0[(size_t)c * LEN + reflmap(sh)]);
            xt[xtaddr(r, c)] = (unsigned)lo | ((unsigned)hi << 16);
        }
    }

    // ---- per-thread (i0, frac) for its column tc, k = 0..4 ----
    int i0r[KS], r0r[KS]; float frr[KS];
    bool fast = true;
    #pragma unroll
    for (int k = 0; k < KS; ++k) {
        float T = (float)(tc + k) + ofr[k];
        T = fminf(fmaxf(T, 0.0f), (float)(LP - 1));
        int i0 = (int)floorf(T);
        i0 = min(i0, LP - 2); i0 = max(i0, 0);
        i0r[k] = i0;
        frr[k] = T - (float)i0;
        r0r[k] = i0 - S0;
        fast = fast && ((unsigned)(i0 - S0) <= (unsigned)(XW - 1));
    }
    __syncthreads();

    f32x4 acc0 = {}, acc1 = {}, acc2 = {}, acc3 = {};
    const unsigned short* wfl = wf + (size_t)lane * 8;

#define LERP2(pk, e, word, f)                                                  \
    {                                                                          \
        float g0 = __builtin_bit_cast(float, (word) << 16);                    \
        float g1 = __builtin_bit_cast(float, (word) & 0xFFFF0000u);            \
        pk[e] = bf16r(fmaf(f, g1 - g0, g0));                                   \
    }

#define GSTEP(kk, CHECKED)                                                     \
    {                                                                          \
        const int k  = (kk) >> 1;                                              \
        const int m  = (((kk) & 1) << 2) + s;        /* chunk 0..7 */          \
        const float f = frr[k];                                                \
        ushort8 pk;                                                            \
        if (!(CHECKED) || (unsigned)r0r[k] <= (unsigned)(XW - 1)) {            \
            const int r0 = r0r[k];                                             \
            const int sw = (r0 & 15);                                          \
            uint4 u0 = *(const uint4*)&xt[r0 * 64 + (((2*m)     ^ sw) << 2)];  \
            uint4 u1 = *(const uint4*)&xt[r0 * 64 + (((2*m + 1) ^ sw) << 2)];  \
            LERP2(pk, 0, u0.x, f) LERP2(pk, 1, u0.y, f)                        \
            LERP2(pk, 2, u0.z, f) LERP2(pk, 3, u0.w, f)                        \
            LERP2(pk, 4, u1.x, f) LERP2(pk, 5, u1.y, f)                        \
            LERP2(pk, 6, u1.z, f) LERP2(pk, 7, u1.w, f)                        \
        } else {                                                               \
            int j0 = reflmap(i0r[k]), j1 = reflmap(i0r[k] + 1);                \
            const float* xc = xb0 + (size_t)(m << 3) * LEN;                    \
            _Pragma("unroll")                                                  \
            for (int e = 0; e < 8; ++e) {                                      \
                float g0 = xc[j0], g1 = xc[j1];                                \
                pk[e] = bf16r(fmaf(f, g1 - g0, g0));                           \
                xc += LEN;                                                     \
            }                                                                  \
        }                                                                      \
        short8 bv = __builtin_bit_cast(short8, pk);                            \
        short8 a0 = *(const short8*)&wfl[(0 * 10 + (kk)) * 512];               \
        short8 a1 = *(const short8*)&wfl[(1 * 10 + (kk)) * 512];               \
        short8 a2 = *(const short8*)&wfl[(2 * 10 + (kk)) * 512];               \
        short8 a3 = *(const short8*)&wfl[(3 * 10 + (kk)) * 512];               \
        acc0 = __builtin_amdgcn_mfma_f32_16x16x32_bf16(a0, bv, acc0, 0, 0, 0); \
        acc1 = __builtin_amdgcn_mfma_f32_16x16x32_bf16(a1, bv, acc1, 0, 0, 0); \
        acc2 = __builtin_amdgcn_mfma_f32_16x16x32_bf16(a2, bv, acc2, 0, 0, 0); \
        acc3 = __builtin_amdgcn_mfma_f32_16x16x32_bf16(a3, bv, acc3, 0, 0, 0); \
    }

    if (fast) {
        GSTEP(0,0) GSTEP(1,0) GSTEP(2,0) GSTEP(3,0) GSTEP(4,0)
        GSTEP(5,0) GSTEP(6,0) GSTEP(7,0) GSTEP(8,0) GSTEP(9,0)
    } else {
        GSTEP(0,1) GSTEP(1,1) GSTEP(2,1) GSTEP(3,1) GSTEP(4,1)
        GSTEP(5,1) GSTEP(6,1) GSTEP(7,1) GSTEP(8,1) GSTEP(9,1)
    }
#undef GSTEP
#undef LERP2

    // ---- epilogue: C/D col=lane&15 (=tc), row=(lane>>4)*4+r ----
    #pragma unroll
    for (int ot = 0; ot < 4; ++ot) {
        const f32x4 a = (ot == 0) ? acc0 : (ot == 1) ? acc1 : (ot == 2) ? acc2 : acc3;
        #pragma unroll
        for (int r = 0; r < 4; ++r) {
            int o = ot * 16 + s * 4 + r;
            out[((size_t)(b * COUT + o)) * LEN + tc] = a[r] + bias[o];
        }
    }
}

extern "C" void kernel_launch(void* const* d_in, const int* in_sizes, int n_in,
                              void* d_out, int out_size, void* d_ws, size_t ws_size,
                              hipStream_t stream) {
    const float* x    = (const float*)d_in[0];
    const float* offs = (const float*)d_in[1];
    const float* w    = (const float*)d_in[2];
    const float* bias = (const float*)d_in[3];
    float* out = (float*)d_out;
    unsigned short* wf = (unsigned short*)d_ws;   // 40960 B

    wfrag_kernel<<<80, 256, 0, stream>>>(w, wf);
    deform_mfma_kernel<<<BATCH * (LEN / TT), 256, 0, stream>>>(x, offs, wf, bias, out);
}